// Round 2
// baseline (749.017 us; speedup 1.0000x reference)
//
#include <hip/hip_runtime.h>
#include <stdint.h>

// ---------------------------------------------------------------------------
// GraphSAGE(min) x3 + BatchNorm + ReLU + log_softmax, fp32, MI355X (gfx950)
//
// R1: replace atomicMin scatter (130us x3, atomic-bound) with CSR built once
//     (hist + scan + fill) and an atomic-free segmented-min gather per layer.
//     BN partials now per-block slots (no atomics, no zeroing).
// ---------------------------------------------------------------------------

// ---------------------------------------------------------------------------
// zero degree array + detect edge dtype (int64 => odd int32 slots all zero)
__global__ __launch_bounds__(256)
void k_prep(int* __restrict__ deg, int n_nodes, const int* __restrict__ ei32,
            int* __restrict__ flag) {
    int i = blockIdx.x * blockDim.x + threadIdx.x;
    int stride = gridDim.x * blockDim.x;
    for (int j = i; j < n_nodes; j += stride) deg[j] = 0;
    if (i == 0) {
        int allzero = 1;
        for (int t = 1; t < 32; t += 2) allzero &= (ei32[t] == 0);
        *flag = allzero;
    }
}

// ---------------------------------------------------------------------------
__global__ __launch_bounds__(256)
void k_hist(const void* __restrict__ ei, int n_edges, int* __restrict__ deg,
            const int* __restrict__ flag) {
    const bool is64 = (*flag != 0);
    const int* e32 = (const int*)ei;
    const long long* e64 = (const long long*)ei;
    int i = blockIdx.x * blockDim.x + threadIdx.x;
    int stride = gridDim.x * blockDim.x;
    for (int e = i; e < n_edges; e += stride) {
        int d = is64 ? (int)e64[n_edges + e] : e32[n_edges + e];
        atomicAdd(&deg[d], 1);
    }
}

// ---------------------------------------------------------------------------
// single-block exclusive scan: rowptr[0..n], cursor = rowptr[0..n)
__global__ __launch_bounds__(1024)
void k_scan(const int* __restrict__ deg, int* __restrict__ rowptr,
            int* __restrict__ cursor, int n) {
    __shared__ int part[1024];
    const int t = threadIdx.x;
    const int chunk = (n + 1023) >> 10;
    const int beg = t * chunk, end = min(beg + chunk, n);
    int s = 0;
    for (int i = beg; i < end; ++i) s += deg[i];
    part[t] = s;
    __syncthreads();
    for (int off = 1; off < 1024; off <<= 1) {
        int v = (t >= off) ? part[t - off] : 0;
        __syncthreads();
        part[t] += v;
        __syncthreads();
    }
    int run = (t == 0) ? 0 : part[t - 1];
    for (int i = beg; i < end; ++i) {
        rowptr[i] = run;
        cursor[i] = run;
        run += deg[i];
    }
    if (t == 0) rowptr[n] = part[1023];
}

// ---------------------------------------------------------------------------
__global__ __launch_bounds__(256)
void k_fill(const void* __restrict__ ei, int n_edges, int* __restrict__ cursor,
            int* __restrict__ csr, const int* __restrict__ flag) {
    const bool is64 = (*flag != 0);
    const int* e32 = (const int*)ei;
    const long long* e64 = (const long long*)ei;
    int i = blockIdx.x * blockDim.x + threadIdx.x;
    int stride = gridDim.x * blockDim.x;
    for (int e = i; e < n_edges; e += stride) {
        int s, d;
        if (is64) { s = (int)e64[e]; d = (int)e64[n_edges + e]; }
        else      { s = e32[e];      d = e32[n_edges + e]; }
        int pos = atomicAdd(&cursor[d], 1);
        csr[pos] = s;
    }
}

// ---------------------------------------------------------------------------
// one wave per dst node, lane = channel; segmented min over CSR, no atomics.
__global__ __launch_bounds__(256)
void k_aggregate(const float* __restrict__ x, const int* __restrict__ rowptr,
                 const int* __restrict__ csr, float* __restrict__ agg,
                 int n_nodes) {
    const int lane = threadIdx.x & 63;
    const int wave = (blockIdx.x * blockDim.x + threadIdx.x) >> 6;
    const int nwaves = (gridDim.x * blockDim.x) >> 6;
    for (int n = wave; n < n_nodes; n += nwaves) {
        const int beg = rowptr[n], end = rowptr[n + 1];
        float m = __builtin_inff();
        int e = beg;
        for (; e + 4 <= end; e += 4) {  // 4 independent gathers in flight
            int s0 = csr[e], s1 = csr[e + 1], s2 = csr[e + 2], s3 = csr[e + 3];
            float v0 = x[(size_t)s0 * 64 + lane];
            float v1 = x[(size_t)s1 * 64 + lane];
            float v2 = x[(size_t)s2 * 64 + lane];
            float v3 = x[(size_t)s3 * 64 + lane];
            m = fminf(m, fminf(fminf(v0, v1), fminf(v2, v3)));
        }
        for (; e < end; ++e) {
            int s = csr[e];
            m = fminf(m, x[(size_t)s * 64 + lane]);
        }
        agg[(size_t)n * 64 + lane] = (end > beg) ? m : 0.0f;  // empty -> 0
    }
}

// ---------------------------------------------------------------------------
// 64->64: block = 256 thr = 4 nodes x 64 ch. W in LDS. BN partials per block.
__global__ __launch_bounds__(256)
void k_gemm64(const float* __restrict__ agg, const float* __restrict__ xin,
              const float* __restrict__ Wl, const float* __restrict__ bl,
              const float* __restrict__ Wr, float* __restrict__ hout,
              double* __restrict__ psum, double* __restrict__ psq, int n_nodes) {
    __shared__ float sWl[64][64];
    __shared__ float sWr[64][64];
    __shared__ float rowA[4][64];
    __shared__ float rowX[4][64];
    __shared__ double red[4][64];
    const int t = threadIdx.x, c = t & 63, ln = t >> 6;
    for (int i = t; i < 4096; i += 256) {
        ((float*)sWl)[i] = Wl[i];
        ((float*)sWr)[i] = Wr[i];
    }
    const float bc = bl[c];
    double lsum = 0.0, lsq = 0.0;
    const int nchunk = (n_nodes + 3) >> 2;
    for (int chunk = blockIdx.x; chunk < nchunk; chunk += gridDim.x) {
        const int node = chunk * 4 + ln;
        __syncthreads();  // also covers first-use of sWl/sWr
        if (node < n_nodes) {
            rowA[ln][c] = agg[(size_t)node * 64 + c];
            rowX[ln][c] = xin[(size_t)node * 64 + c];
        }
        __syncthreads();
        if (node < n_nodes) {
            float acc = bc;
#pragma unroll
            for (int k = 0; k < 64; ++k)
                acc = fmaf(rowA[ln][k], sWl[k][c], fmaf(rowX[ln][k], sWr[k][c], acc));
            hout[(size_t)node * 64 + c] = acc;
            lsum += (double)acc;
            lsq  += (double)acc * (double)acc;
        }
    }
    // block-local reduce over ln, plain store to private slot (no atomics)
    __syncthreads();
    red[ln][c] = lsum;
    __syncthreads();
    if (ln == 0)
        psum[(size_t)blockIdx.x * 64 + c] = red[0][c] + red[1][c] + red[2][c] + red[3][c];
    __syncthreads();
    red[ln][c] = lsq;
    __syncthreads();
    if (ln == 0)
        psq[(size_t)blockIdx.x * 64 + c] = red[0][c] + red[1][c] + red[2][c] + red[3][c];
}

// ---------------------------------------------------------------------------
__global__ void k_finalize(const double* __restrict__ psum,
                           const double* __restrict__ psq,
                           float* __restrict__ mu, float* __restrict__ istd,
                           int n_nodes, int nblocks) {
    const int c = threadIdx.x;  // 64 threads
    double s = 0.0, q = 0.0;
    for (int b = 0; b < nblocks; ++b) { s += psum[(size_t)b * 64 + c]; q += psq[(size_t)b * 64 + c]; }
    double m = s / n_nodes;
    double var = q / n_nodes - m * m;
    mu[c] = (float)m;
    istd[c] = (float)(1.0 / sqrt(var + 1e-5));
}

// ---------------------------------------------------------------------------
__global__ __launch_bounds__(256)
void k_bnrelu(float* __restrict__ h, const float* __restrict__ g,
              const float* __restrict__ be, const float* __restrict__ mu,
              const float* __restrict__ istd, int ntot) {
    int i = blockIdx.x * blockDim.x + threadIdx.x;
    int stride = gridDim.x * blockDim.x;
    for (int j = i; j < ntot; j += stride) {
        int c = j & 63;
        float v = (h[j] - mu[c]) * istd[c] * g[c] + be[c];
        h[j] = fmaxf(v, 0.0f);
    }
}

// ---------------------------------------------------------------------------
// 64->16 GEMM + log_softmax. Block = 16 nodes x 16 ch.
__global__ __launch_bounds__(256)
void k_l3(const float* __restrict__ agg, const float* __restrict__ xin,
          const float* __restrict__ W3l, const float* __restrict__ b3,
          const float* __restrict__ W3r, float* __restrict__ out, int n_nodes) {
    __shared__ float sWl[64][16];
    __shared__ float sWr[64][16];
    __shared__ float rowA[16][65];
    __shared__ float rowX[16][65];
    const int t = threadIdx.x;
    for (int i = t; i < 1024; i += 256) {
        ((float*)sWl)[i] = W3l[i];
        ((float*)sWr)[i] = W3r[i];
    }
    const int base = blockIdx.x * 16;
#pragma unroll
    for (int i = 0; i < 4; ++i) {
        int j = t + i * 256;
        int nd = j >> 6, k = j & 63;
        int gnode = base + nd;
        if (gnode < n_nodes) {
            rowA[nd][k] = agg[(size_t)gnode * 64 + k];
            rowX[nd][k] = xin[(size_t)gnode * 64 + k];
        } else {
            rowA[nd][k] = 0.0f;
            rowX[nd][k] = 0.0f;
        }
    }
    __syncthreads();
    const int n = t >> 4, c = t & 15;
    float acc = b3[c];
#pragma unroll
    for (int k = 0; k < 64; ++k)
        acc = fmaf(rowA[n][k], sWl[k][c], fmaf(rowX[n][k], sWr[k][c], acc));
    float m = acc;
    for (int off = 8; off; off >>= 1) m = fmaxf(m, __shfl_xor(m, off, 16));
    float ex = expf(acc - m);
    float ssum = ex;
    for (int off = 8; off; off >>= 1) ssum += __shfl_xor(ssum, off, 16);
    if (base + n < n_nodes)
        out[(size_t)(base + n) * 16 + c] = (acc - m) - logf(ssum);
}

// ---------------------------------------------------------------------------
extern "C" void kernel_launch(void* const* d_in, const int* in_sizes, int n_in,
                              void* d_out, int out_size, void* d_ws, size_t ws_size,
                              hipStream_t stream) {
    (void)n_in; (void)out_size; (void)ws_size;
    const float* x   = (const float*)d_in[0];
    const void*  ei  = d_in[1];
    const float* W1l = (const float*)d_in[2];
    const float* b1  = (const float*)d_in[3];
    const float* W1r = (const float*)d_in[4];
    const float* g1  = (const float*)d_in[5];
    const float* be1 = (const float*)d_in[6];
    const float* W2l = (const float*)d_in[7];
    const float* b2  = (const float*)d_in[8];
    const float* W2r = (const float*)d_in[9];
    const float* g2  = (const float*)d_in[10];
    const float* be2 = (const float*)d_in[11];
    const float* W3l = (const float*)d_in[12];
    const float* b3  = (const float*)d_in[13];
    const float* W3r = (const float*)d_in[14];
    float* out = (float*)d_out;

    const int n_nodes = in_sizes[0] / 64;
    const int n_edges = in_sizes[1] / 2;
    const int nAgg = n_nodes * 64;

    size_t off = 0;
    auto alloc = [&](size_t bytes) {
        void* p = (char*)d_ws + off;
        off = (off + bytes + 255) & ~(size_t)255;
        return p;
    };
    float* agg    = (float*)alloc((size_t)nAgg * 4);
    float* hA     = (float*)alloc((size_t)nAgg * 4);
    float* hB     = (float*)alloc((size_t)nAgg * 4);
    int*   csr    = (int*)  alloc((size_t)n_edges * 4);
    int*   rowptr = (int*)  alloc((size_t)(n_nodes + 1) * 4);
    int*   cursor = (int*)  alloc((size_t)n_nodes * 4);
    int*   deg    = (int*)  alloc((size_t)n_nodes * 4);
    const int GG = 512;
    double* psum  = (double*)alloc((size_t)GG * 64 * 8);
    double* psq   = (double*)alloc((size_t)GG * 64 * 8);
    float*  mu    = (float*) alloc(64 * 4);
    float*  istd  = (float*) alloc(64 * 4);
    int*    flag  = (int*)   alloc(4);

    const int GP = 256, GH = 1024, GF = 1024, GA = 2048, GN = 2048;
    const int GL3 = (n_nodes + 15) / 16;

    // ---- build CSR once ----
    k_prep<<<GP, 256, 0, stream>>>(deg, n_nodes, (const int*)ei, flag);
    k_hist<<<GH, 256, 0, stream>>>(ei, n_edges, deg, flag);
    k_scan<<<1, 1024, 0, stream>>>(deg, rowptr, cursor, n_nodes);
    k_fill<<<GF, 256, 0, stream>>>(ei, n_edges, cursor, csr, flag);

    // ---- layer 1 ----
    k_aggregate<<<GA, 256, 0, stream>>>(x, rowptr, csr, agg, n_nodes);
    k_gemm64  <<<GG, 256, 0, stream>>>(agg, x, W1l, b1, W1r, hA, psum, psq, n_nodes);
    k_finalize<<<1, 64, 0, stream>>>(psum, psq, mu, istd, n_nodes, GG);
    k_bnrelu  <<<GN, 256, 0, stream>>>(hA, g1, be1, mu, istd, nAgg);
    // ---- layer 2 ----
    k_aggregate<<<GA, 256, 0, stream>>>(hA, rowptr, csr, agg, n_nodes);
    k_gemm64  <<<GG, 256, 0, stream>>>(agg, hA, W2l, b2, W2r, hB, psum, psq, n_nodes);
    k_finalize<<<1, 64, 0, stream>>>(psum, psq, mu, istd, n_nodes, GG);
    k_bnrelu  <<<GN, 256, 0, stream>>>(hB, g2, be2, mu, istd, nAgg);
    // ---- layer 3 ----
    k_aggregate<<<GA, 256, 0, stream>>>(hB, rowptr, csr, agg, n_nodes);
    k_l3      <<<GL3, 256, 0, stream>>>(agg, hB, W3l, b3, W3r, out, n_nodes);
}

// Round 3
// 524.105 us; speedup vs baseline: 1.4291x; 1.4291x over previous
//
#include <hip/hip_runtime.h>
#include <stdint.h>

// ---------------------------------------------------------------------------
// GraphSAGE(min) x3 + BatchNorm + ReLU + log_softmax, fp32, MI355X (gfx950)
//
// R1: CSR (hist+scan+fill) once, atomic-free segmented-min gather per layer.
// R2: k_finalize was 134us x2 (single 64-thread block serially reducing 512
//     slot-rows — latency-bound). Now 1024 threads, 16 groups x 64 ch, LDS
//     tree. Also float4-vectorized k_bnrelu.
// ---------------------------------------------------------------------------

// ---------------------------------------------------------------------------
// zero degree array + detect edge dtype (int64 => odd int32 slots all zero)
__global__ __launch_bounds__(256)
void k_prep(int* __restrict__ deg, int n_nodes, const int* __restrict__ ei32,
            int* __restrict__ flag) {
    int i = blockIdx.x * blockDim.x + threadIdx.x;
    int stride = gridDim.x * blockDim.x;
    for (int j = i; j < n_nodes; j += stride) deg[j] = 0;
    if (i == 0) {
        int allzero = 1;
        for (int t = 1; t < 32; t += 2) allzero &= (ei32[t] == 0);
        *flag = allzero;
    }
}

// ---------------------------------------------------------------------------
__global__ __launch_bounds__(256)
void k_hist(const void* __restrict__ ei, int n_edges, int* __restrict__ deg,
            const int* __restrict__ flag) {
    const bool is64 = (*flag != 0);
    const int* e32 = (const int*)ei;
    const long long* e64 = (const long long*)ei;
    int i = blockIdx.x * blockDim.x + threadIdx.x;
    int stride = gridDim.x * blockDim.x;
    for (int e = i; e < n_edges; e += stride) {
        int d = is64 ? (int)e64[n_edges + e] : e32[n_edges + e];
        atomicAdd(&deg[d], 1);
    }
}

// ---------------------------------------------------------------------------
// single-block exclusive scan: rowptr[0..n], cursor = rowptr[0..n)
__global__ __launch_bounds__(1024)
void k_scan(const int* __restrict__ deg, int* __restrict__ rowptr,
            int* __restrict__ cursor, int n) {
    __shared__ int part[1024];
    const int t = threadIdx.x;
    const int chunk = (n + 1023) >> 10;
    const int beg = t * chunk, end = min(beg + chunk, n);
    int s = 0;
    for (int i = beg; i < end; ++i) s += deg[i];
    part[t] = s;
    __syncthreads();
    for (int off = 1; off < 1024; off <<= 1) {
        int v = (t >= off) ? part[t - off] : 0;
        __syncthreads();
        part[t] += v;
        __syncthreads();
    }
    int run = (t == 0) ? 0 : part[t - 1];
    for (int i = beg; i < end; ++i) {
        rowptr[i] = run;
        cursor[i] = run;
        run += deg[i];
    }
    if (t == 0) rowptr[n] = part[1023];
}

// ---------------------------------------------------------------------------
__global__ __launch_bounds__(256)
void k_fill(const void* __restrict__ ei, int n_edges, int* __restrict__ cursor,
            int* __restrict__ csr, const int* __restrict__ flag) {
    const bool is64 = (*flag != 0);
    const int* e32 = (const int*)ei;
    const long long* e64 = (const long long*)ei;
    int i = blockIdx.x * blockDim.x + threadIdx.x;
    int stride = gridDim.x * blockDim.x;
    for (int e = i; e < n_edges; e += stride) {
        int s, d;
        if (is64) { s = (int)e64[e]; d = (int)e64[n_edges + e]; }
        else      { s = e32[e];      d = e32[n_edges + e]; }
        int pos = atomicAdd(&cursor[d], 1);
        csr[pos] = s;
    }
}

// ---------------------------------------------------------------------------
// one wave per dst node, lane = channel; segmented min over CSR, no atomics.
__global__ __launch_bounds__(256)
void k_aggregate(const float* __restrict__ x, const int* __restrict__ rowptr,
                 const int* __restrict__ csr, float* __restrict__ agg,
                 int n_nodes) {
    const int lane = threadIdx.x & 63;
    const int wave = (blockIdx.x * blockDim.x + threadIdx.x) >> 6;
    const int nwaves = (gridDim.x * blockDim.x) >> 6;
    for (int n = wave; n < n_nodes; n += nwaves) {
        const int beg = rowptr[n], end = rowptr[n + 1];
        float m = __builtin_inff();
        int e = beg;
        for (; e + 4 <= end; e += 4) {  // 4 independent gathers in flight
            int s0 = csr[e], s1 = csr[e + 1], s2 = csr[e + 2], s3 = csr[e + 3];
            float v0 = x[(size_t)s0 * 64 + lane];
            float v1 = x[(size_t)s1 * 64 + lane];
            float v2 = x[(size_t)s2 * 64 + lane];
            float v3 = x[(size_t)s3 * 64 + lane];
            m = fminf(m, fminf(fminf(v0, v1), fminf(v2, v3)));
        }
        for (; e < end; ++e) {
            int s = csr[e];
            m = fminf(m, x[(size_t)s * 64 + lane]);
        }
        agg[(size_t)n * 64 + lane] = (end > beg) ? m : 0.0f;  // empty -> 0
    }
}

// ---------------------------------------------------------------------------
// 64->64: block = 256 thr = 4 nodes x 64 ch. W in LDS. BN partials per block.
__global__ __launch_bounds__(256)
void k_gemm64(const float* __restrict__ agg, const float* __restrict__ xin,
              const float* __restrict__ Wl, const float* __restrict__ bl,
              const float* __restrict__ Wr, float* __restrict__ hout,
              double* __restrict__ psum, double* __restrict__ psq, int n_nodes) {
    __shared__ float sWl[64][64];
    __shared__ float sWr[64][64];
    __shared__ float rowA[4][64];
    __shared__ float rowX[4][64];
    __shared__ double red[4][64];
    const int t = threadIdx.x, c = t & 63, ln = t >> 6;
    for (int i = t; i < 4096; i += 256) {
        ((float*)sWl)[i] = Wl[i];
        ((float*)sWr)[i] = Wr[i];
    }
    const float bc = bl[c];
    double lsum = 0.0, lsq = 0.0;
    const int nchunk = (n_nodes + 3) >> 2;
    for (int chunk = blockIdx.x; chunk < nchunk; chunk += gridDim.x) {
        const int node = chunk * 4 + ln;
        __syncthreads();  // also covers first-use of sWl/sWr
        if (node < n_nodes) {
            rowA[ln][c] = agg[(size_t)node * 64 + c];
            rowX[ln][c] = xin[(size_t)node * 64 + c];
        }
        __syncthreads();
        if (node < n_nodes) {
            float acc = bc;
#pragma unroll
            for (int k = 0; k < 64; ++k)
                acc = fmaf(rowA[ln][k], sWl[k][c], fmaf(rowX[ln][k], sWr[k][c], acc));
            hout[(size_t)node * 64 + c] = acc;
            lsum += (double)acc;
            lsq  += (double)acc * (double)acc;
        }
    }
    // block-local reduce over ln, plain store to private slot (no atomics)
    __syncthreads();
    red[ln][c] = lsum;
    __syncthreads();
    if (ln == 0)
        psum[(size_t)blockIdx.x * 64 + c] = red[0][c] + red[1][c] + red[2][c] + red[3][c];
    __syncthreads();
    red[ln][c] = lsq;
    __syncthreads();
    if (ln == 0)
        psq[(size_t)blockIdx.x * 64 + c] = red[0][c] + red[1][c] + red[2][c] + red[3][c];
}

// ---------------------------------------------------------------------------
// parallel finalize: 1024 thr = 16 groups x 64 ch, grid-stride over slots.
__global__ __launch_bounds__(1024)
void k_finalize(const double* __restrict__ psum, const double* __restrict__ psq,
                float* __restrict__ mu, float* __restrict__ istd,
                int n_nodes, int nblocks) {
    __shared__ double s_s[16][64];
    __shared__ double s_q[16][64];
    const int t = threadIdx.x;
    const int c = t & 63, g = t >> 6;  // 16 groups
    double s = 0.0, q = 0.0;
    for (int b = g; b < nblocks; b += 16) {
        s += psum[(size_t)b * 64 + c];
        q += psq[(size_t)b * 64 + c];
    }
    s_s[g][c] = s;
    s_q[g][c] = q;
    __syncthreads();
    if (g == 0) {
        double S = 0.0, Q = 0.0;
#pragma unroll
        for (int i = 0; i < 16; ++i) { S += s_s[i][c]; Q += s_q[i][c]; }
        double m = S / n_nodes;
        double var = Q / n_nodes - m * m;
        mu[c] = (float)m;
        istd[c] = (float)(1.0 / sqrt(var + 1e-5));
    }
}

// ---------------------------------------------------------------------------
// float4-vectorized BN+ReLU (64 ch = 16 float4 groups per node row)
__global__ __launch_bounds__(256)
void k_bnrelu(float* __restrict__ h, const float* __restrict__ g,
              const float* __restrict__ be, const float* __restrict__ mu,
              const float* __restrict__ istd, int ntot4) {
    int i = blockIdx.x * blockDim.x + threadIdx.x;
    int stride = gridDim.x * blockDim.x;
    float4* h4 = (float4*)h;
    for (int j = i; j < ntot4; j += stride) {
        int c0 = (j << 2) & 63;
        float4 v = h4[j];
        v.x = fmaxf((v.x - mu[c0 + 0]) * istd[c0 + 0] * g[c0 + 0] + be[c0 + 0], 0.0f);
        v.y = fmaxf((v.y - mu[c0 + 1]) * istd[c0 + 1] * g[c0 + 1] + be[c0 + 1], 0.0f);
        v.z = fmaxf((v.z - mu[c0 + 2]) * istd[c0 + 2] * g[c0 + 2] + be[c0 + 2], 0.0f);
        v.w = fmaxf((v.w - mu[c0 + 3]) * istd[c0 + 3] * g[c0 + 3] + be[c0 + 3], 0.0f);
        h4[j] = v;
    }
}

// ---------------------------------------------------------------------------
// 64->16 GEMM + log_softmax. Block = 16 nodes x 16 ch.
__global__ __launch_bounds__(256)
void k_l3(const float* __restrict__ agg, const float* __restrict__ xin,
          const float* __restrict__ W3l, const float* __restrict__ b3,
          const float* __restrict__ W3r, float* __restrict__ out, int n_nodes) {
    __shared__ float sWl[64][16];
    __shared__ float sWr[64][16];
    __shared__ float rowA[16][65];
    __shared__ float rowX[16][65];
    const int t = threadIdx.x;
    for (int i = t; i < 1024; i += 256) {
        ((float*)sWl)[i] = W3l[i];
        ((float*)sWr)[i] = W3r[i];
    }
    const int base = blockIdx.x * 16;
#pragma unroll
    for (int i = 0; i < 4; ++i) {
        int j = t + i * 256;
        int nd = j >> 6, k = j & 63;
        int gnode = base + nd;
        if (gnode < n_nodes) {
            rowA[nd][k] = agg[(size_t)gnode * 64 + k];
            rowX[nd][k] = xin[(size_t)gnode * 64 + k];
        } else {
            rowA[nd][k] = 0.0f;
            rowX[nd][k] = 0.0f;
        }
    }
    __syncthreads();
    const int n = t >> 4, c = t & 15;
    float acc = b3[c];
#pragma unroll
    for (int k = 0; k < 64; ++k)
        acc = fmaf(rowA[n][k], sWl[k][c], fmaf(rowX[n][k], sWr[k][c], acc));
    float m = acc;
    for (int off = 8; off; off >>= 1) m = fmaxf(m, __shfl_xor(m, off, 16));
    float ex = expf(acc - m);
    float ssum = ex;
    for (int off = 8; off; off >>= 1) ssum += __shfl_xor(ssum, off, 16);
    if (base + n < n_nodes)
        out[(size_t)(base + n) * 16 + c] = (acc - m) - logf(ssum);
}

// ---------------------------------------------------------------------------
extern "C" void kernel_launch(void* const* d_in, const int* in_sizes, int n_in,
                              void* d_out, int out_size, void* d_ws, size_t ws_size,
                              hipStream_t stream) {
    (void)n_in; (void)out_size; (void)ws_size;
    const float* x   = (const float*)d_in[0];
    const void*  ei  = d_in[1];
    const float* W1l = (const float*)d_in[2];
    const float* b1  = (const float*)d_in[3];
    const float* W1r = (const float*)d_in[4];
    const float* g1  = (const float*)d_in[5];
    const float* be1 = (const float*)d_in[6];
    const float* W2l = (const float*)d_in[7];
    const float* b2  = (const float*)d_in[8];
    const float* W2r = (const float*)d_in[9];
    const float* g2  = (const float*)d_in[10];
    const float* be2 = (const float*)d_in[11];
    const float* W3l = (const float*)d_in[12];
    const float* b3  = (const float*)d_in[13];
    const float* W3r = (const float*)d_in[14];
    float* out = (float*)d_out;

    const int n_nodes = in_sizes[0] / 64;
    const int n_edges = in_sizes[1] / 2;
    const int nAgg = n_nodes * 64;

    size_t off = 0;
    auto alloc = [&](size_t bytes) {
        void* p = (char*)d_ws + off;
        off = (off + bytes + 255) & ~(size_t)255;
        return p;
    };
    float* agg    = (float*)alloc((size_t)nAgg * 4);
    float* hA     = (float*)alloc((size_t)nAgg * 4);
    float* hB     = (float*)alloc((size_t)nAgg * 4);
    int*   csr    = (int*)  alloc((size_t)n_edges * 4);
    int*   rowptr = (int*)  alloc((size_t)(n_nodes + 1) * 4);
    int*   cursor = (int*)  alloc((size_t)n_nodes * 4);
    int*   deg    = (int*)  alloc((size_t)n_nodes * 4);
    const int GG = 512;
    double* psum  = (double*)alloc((size_t)GG * 64 * 8);
    double* psq   = (double*)alloc((size_t)GG * 64 * 8);
    float*  mu    = (float*) alloc(64 * 4);
    float*  istd  = (float*) alloc(64 * 4);
    int*    flag  = (int*)   alloc(4);

    const int GP = 256, GH = 1024, GF = 1024, GA = 2048, GN = 1024;
    const int GL3 = (n_nodes + 15) / 16;

    // ---- build CSR once ----
    k_prep<<<GP, 256, 0, stream>>>(deg, n_nodes, (const int*)ei, flag);
    k_hist<<<GH, 256, 0, stream>>>(ei, n_edges, deg, flag);
    k_scan<<<1, 1024, 0, stream>>>(deg, rowptr, cursor, n_nodes);
    k_fill<<<GF, 256, 0, stream>>>(ei, n_edges, cursor, csr, flag);

    // ---- layer 1 ----
    k_aggregate<<<GA, 256, 0, stream>>>(x, rowptr, csr, agg, n_nodes);
    k_gemm64  <<<GG, 256, 0, stream>>>(agg, x, W1l, b1, W1r, hA, psum, psq, n_nodes);
    k_finalize<<<1, 1024, 0, stream>>>(psum, psq, mu, istd, n_nodes, GG);
    k_bnrelu  <<<GN, 256, 0, stream>>>(hA, g1, be1, mu, istd, nAgg / 4);
    // ---- layer 2 ----
    k_aggregate<<<GA, 256, 0, stream>>>(hA, rowptr, csr, agg, n_nodes);
    k_gemm64  <<<GG, 256, 0, stream>>>(agg, hA, W2l, b2, W2r, hB, psum, psq, n_nodes);
    k_finalize<<<1, 1024, 0, stream>>>(psum, psq, mu, istd, n_nodes, GG);
    k_bnrelu  <<<GN, 256, 0, stream>>>(hB, g2, be2, mu, istd, nAgg / 4);
    // ---- layer 3 ----
    k_aggregate<<<GA, 256, 0, stream>>>(hB, rowptr, csr, agg, n_nodes);
    k_l3      <<<GL3, 256, 0, stream>>>(agg, hB, W3l, b3, W3r, out, n_nodes);
}

// Round 4
// 402.022 us; speedup vs baseline: 1.8631x; 1.3037x over previous
//
#include <hip/hip_runtime.h>
#include <stdint.h>

// ---------------------------------------------------------------------------
// GraphSAGE(min) x3 + BatchNorm + ReLU + log_softmax, fp32, MI355X (gfx950)
//
// R1: CSR (hist+scan+fill) once, atomic-free segmented-min gather per layer.
// R2: parallel k_finalize (was 134us single-block serial reduce).
// R3: hierarchical 3-kernel scan (k_scan was 110us: single block, serial
//     chunk walk on one CU). scan1: block sums; scan2: scan of block sums
//     (1 small block); scan3: per-block LDS scan + offset.
// ---------------------------------------------------------------------------

// ---------------------------------------------------------------------------
// zero degree array + detect edge dtype (int64 => odd int32 slots all zero)
__global__ __launch_bounds__(256)
void k_prep(int* __restrict__ deg, int n_nodes, const int* __restrict__ ei32,
            int* __restrict__ flag) {
    int i = blockIdx.x * blockDim.x + threadIdx.x;
    int stride = gridDim.x * blockDim.x;
    for (int j = i; j < n_nodes; j += stride) deg[j] = 0;
    if (i == 0) {
        int allzero = 1;
        for (int t = 1; t < 32; t += 2) allzero &= (ei32[t] == 0);
        *flag = allzero;
    }
}

// ---------------------------------------------------------------------------
__global__ __launch_bounds__(256)
void k_hist(const void* __restrict__ ei, int n_edges, int* __restrict__ deg,
            const int* __restrict__ flag) {
    const bool is64 = (*flag != 0);
    const int* e32 = (const int*)ei;
    const long long* e64 = (const long long*)ei;
    int i = blockIdx.x * blockDim.x + threadIdx.x;
    int stride = gridDim.x * blockDim.x;
    for (int e = i; e < n_edges; e += stride) {
        int d = is64 ? (int)e64[n_edges + e] : e32[n_edges + e];
        atomicAdd(&deg[d], 1);
    }
}

// ---------------------------------------------------------------------------
// hierarchical scan, step 1: per-block sums of 256-element chunks
__global__ __launch_bounds__(256)
void k_scan1(const int* __restrict__ deg, int* __restrict__ bsum, int n) {
    __shared__ int red[256];
    const int t = threadIdx.x;
    const int i = blockIdx.x * 256 + t;
    red[t] = (i < n) ? deg[i] : 0;
    __syncthreads();
    for (int off = 128; off; off >>= 1) {
        if (t < off) red[t] += red[t + off];
        __syncthreads();
    }
    if (t == 0) bsum[blockIdx.x] = red[0];
}

// ---------------------------------------------------------------------------
// step 2: single small block scans the <=1024 block sums
__global__ __launch_bounds__(1024)
void k_scan2(const int* __restrict__ bsum, int* __restrict__ boffs,
             int nb, int* __restrict__ rowptr, int n) {
    __shared__ int part[1024];
    const int t = threadIdx.x;
    part[t] = (t < nb) ? bsum[t] : 0;
    __syncthreads();
    for (int off = 1; off < 1024; off <<= 1) {
        int v = (t >= off) ? part[t - off] : 0;
        __syncthreads();
        part[t] += v;
        __syncthreads();
    }
    if (t < nb) boffs[t] = (t == 0) ? 0 : part[t - 1];
    if (t == 0) rowptr[n] = part[nb - 1];
}

// ---------------------------------------------------------------------------
// step 3: per-block exclusive scan + block offset -> rowptr, cursor
__global__ __launch_bounds__(256)
void k_scan3(const int* __restrict__ deg, const int* __restrict__ boffs,
             int* __restrict__ rowptr, int* __restrict__ cursor, int n) {
    __shared__ int part[256];
    const int t = threadIdx.x;
    const int i = blockIdx.x * 256 + t;
    const int d = (i < n) ? deg[i] : 0;
    part[t] = d;
    __syncthreads();
    for (int off = 1; off < 256; off <<= 1) {
        int v = (t >= off) ? part[t - off] : 0;
        __syncthreads();
        part[t] += v;
        __syncthreads();
    }
    if (i < n) {
        int excl = boffs[blockIdx.x] + part[t] - d;
        rowptr[i] = excl;
        cursor[i] = excl;
    }
}

// ---------------------------------------------------------------------------
__global__ __launch_bounds__(256)
void k_fill(const void* __restrict__ ei, int n_edges, int* __restrict__ cursor,
            int* __restrict__ csr, const int* __restrict__ flag) {
    const bool is64 = (*flag != 0);
    const int* e32 = (const int*)ei;
    const long long* e64 = (const long long*)ei;
    int i = blockIdx.x * blockDim.x + threadIdx.x;
    int stride = gridDim.x * blockDim.x;
    for (int e = i; e < n_edges; e += stride) {
        int s, d;
        if (is64) { s = (int)e64[e]; d = (int)e64[n_edges + e]; }
        else      { s = e32[e];      d = e32[n_edges + e]; }
        int pos = atomicAdd(&cursor[d], 1);
        csr[pos] = s;
    }
}

// ---------------------------------------------------------------------------
// one wave per dst node, lane = channel; segmented min over CSR, no atomics.
__global__ __launch_bounds__(256)
void k_aggregate(const float* __restrict__ x, const int* __restrict__ rowptr,
                 const int* __restrict__ csr, float* __restrict__ agg,
                 int n_nodes) {
    const int lane = threadIdx.x & 63;
    const int wave = (blockIdx.x * blockDim.x + threadIdx.x) >> 6;
    const int nwaves = (gridDim.x * blockDim.x) >> 6;
    for (int n = wave; n < n_nodes; n += nwaves) {
        const int beg = rowptr[n], end = rowptr[n + 1];
        float m = __builtin_inff();
        int e = beg;
        for (; e + 4 <= end; e += 4) {  // 4 independent gathers in flight
            int s0 = csr[e], s1 = csr[e + 1], s2 = csr[e + 2], s3 = csr[e + 3];
            float v0 = x[(size_t)s0 * 64 + lane];
            float v1 = x[(size_t)s1 * 64 + lane];
            float v2 = x[(size_t)s2 * 64 + lane];
            float v3 = x[(size_t)s3 * 64 + lane];
            m = fminf(m, fminf(fminf(v0, v1), fminf(v2, v3)));
        }
        for (; e < end; ++e) {
            int s = csr[e];
            m = fminf(m, x[(size_t)s * 64 + lane]);
        }
        agg[(size_t)n * 64 + lane] = (end > beg) ? m : 0.0f;  // empty -> 0
    }
}

// ---------------------------------------------------------------------------
// 64->64: block = 256 thr = 4 nodes x 64 ch. W in LDS. BN partials per block.
__global__ __launch_bounds__(256)
void k_gemm64(const float* __restrict__ agg, const float* __restrict__ xin,
              const float* __restrict__ Wl, const float* __restrict__ bl,
              const float* __restrict__ Wr, float* __restrict__ hout,
              double* __restrict__ psum, double* __restrict__ psq, int n_nodes) {
    __shared__ float sWl[64][64];
    __shared__ float sWr[64][64];
    __shared__ float rowA[4][64];
    __shared__ float rowX[4][64];
    __shared__ double red[4][64];
    const int t = threadIdx.x, c = t & 63, ln = t >> 6;
    for (int i = t; i < 4096; i += 256) {
        ((float*)sWl)[i] = Wl[i];
        ((float*)sWr)[i] = Wr[i];
    }
    const float bc = bl[c];
    double lsum = 0.0, lsq = 0.0;
    const int nchunk = (n_nodes + 3) >> 2;
    for (int chunk = blockIdx.x; chunk < nchunk; chunk += gridDim.x) {
        const int node = chunk * 4 + ln;
        __syncthreads();  // also covers first-use of sWl/sWr
        if (node < n_nodes) {
            rowA[ln][c] = agg[(size_t)node * 64 + c];
            rowX[ln][c] = xin[(size_t)node * 64 + c];
        }
        __syncthreads();
        if (node < n_nodes) {
            float acc = bc;
#pragma unroll
            for (int k = 0; k < 64; ++k)
                acc = fmaf(rowA[ln][k], sWl[k][c], fmaf(rowX[ln][k], sWr[k][c], acc));
            hout[(size_t)node * 64 + c] = acc;
            lsum += (double)acc;
            lsq  += (double)acc * (double)acc;
        }
    }
    // block-local reduce over ln, plain store to private slot (no atomics)
    __syncthreads();
    red[ln][c] = lsum;
    __syncthreads();
    if (ln == 0)
        psum[(size_t)blockIdx.x * 64 + c] = red[0][c] + red[1][c] + red[2][c] + red[3][c];
    __syncthreads();
    red[ln][c] = lsq;
    __syncthreads();
    if (ln == 0)
        psq[(size_t)blockIdx.x * 64 + c] = red[0][c] + red[1][c] + red[2][c] + red[3][c];
}

// ---------------------------------------------------------------------------
// parallel finalize: 1024 thr = 16 groups x 64 ch, grid-stride over slots.
__global__ __launch_bounds__(1024)
void k_finalize(const double* __restrict__ psum, const double* __restrict__ psq,
                float* __restrict__ mu, float* __restrict__ istd,
                int n_nodes, int nblocks) {
    __shared__ double s_s[16][64];
    __shared__ double s_q[16][64];
    const int t = threadIdx.x;
    const int c = t & 63, g = t >> 6;  // 16 groups
    double s = 0.0, q = 0.0;
    for (int b = g; b < nblocks; b += 16) {
        s += psum[(size_t)b * 64 + c];
        q += psq[(size_t)b * 64 + c];
    }
    s_s[g][c] = s;
    s_q[g][c] = q;
    __syncthreads();
    if (g == 0) {
        double S = 0.0, Q = 0.0;
#pragma unroll
        for (int i = 0; i < 16; ++i) { S += s_s[i][c]; Q += s_q[i][c]; }
        double m = S / n_nodes;
        double var = Q / n_nodes - m * m;
        mu[c] = (float)m;
        istd[c] = (float)(1.0 / sqrt(var + 1e-5));
    }
}

// ---------------------------------------------------------------------------
// float4-vectorized BN+ReLU (64 ch = 16 float4 groups per node row)
__global__ __launch_bounds__(256)
void k_bnrelu(float* __restrict__ h, const float* __restrict__ g,
              const float* __restrict__ be, const float* __restrict__ mu,
              const float* __restrict__ istd, int ntot4) {
    int i = blockIdx.x * blockDim.x + threadIdx.x;
    int stride = gridDim.x * blockDim.x;
    float4* h4 = (float4*)h;
    for (int j = i; j < ntot4; j += stride) {
        int c0 = (j << 2) & 63;
        float4 v = h4[j];
        v.x = fmaxf((v.x - mu[c0 + 0]) * istd[c0 + 0] * g[c0 + 0] + be[c0 + 0], 0.0f);
        v.y = fmaxf((v.y - mu[c0 + 1]) * istd[c0 + 1] * g[c0 + 1] + be[c0 + 1], 0.0f);
        v.z = fmaxf((v.z - mu[c0 + 2]) * istd[c0 + 2] * g[c0 + 2] + be[c0 + 2], 0.0f);
        v.w = fmaxf((v.w - mu[c0 + 3]) * istd[c0 + 3] * g[c0 + 3] + be[c0 + 3], 0.0f);
        h4[j] = v;
    }
}

// ---------------------------------------------------------------------------
// 64->16 GEMM + log_softmax. Block = 16 nodes x 16 ch.
__global__ __launch_bounds__(256)
void k_l3(const float* __restrict__ agg, const float* __restrict__ xin,
          const float* __restrict__ W3l, const float* __restrict__ b3,
          const float* __restrict__ W3r, float* __restrict__ out, int n_nodes) {
    __shared__ float sWl[64][16];
    __shared__ float sWr[64][16];
    __shared__ float rowA[16][65];
    __shared__ float rowX[16][65];
    const int t = threadIdx.x;
    for (int i = t; i < 1024; i += 256) {
        ((float*)sWl)[i] = W3l[i];
        ((float*)sWr)[i] = W3r[i];
    }
    const int base = blockIdx.x * 16;
#pragma unroll
    for (int i = 0; i < 4; ++i) {
        int j = t + i * 256;
        int nd = j >> 6, k = j & 63;
        int gnode = base + nd;
        if (gnode < n_nodes) {
            rowA[nd][k] = agg[(size_t)gnode * 64 + k];
            rowX[nd][k] = xin[(size_t)gnode * 64 + k];
        } else {
            rowA[nd][k] = 0.0f;
            rowX[nd][k] = 0.0f;
        }
    }
    __syncthreads();
    const int n = t >> 4, c = t & 15;
    float acc = b3[c];
#pragma unroll
    for (int k = 0; k < 64; ++k)
        acc = fmaf(rowA[n][k], sWl[k][c], fmaf(rowX[n][k], sWr[k][c], acc));
    float m = acc;
    for (int off = 8; off; off >>= 1) m = fmaxf(m, __shfl_xor(m, off, 16));
    float ex = expf(acc - m);
    float ssum = ex;
    for (int off = 8; off; off >>= 1) ssum += __shfl_xor(ssum, off, 16);
    if (base + n < n_nodes)
        out[(size_t)(base + n) * 16 + c] = (acc - m) - logf(ssum);
}

// ---------------------------------------------------------------------------
extern "C" void kernel_launch(void* const* d_in, const int* in_sizes, int n_in,
                              void* d_out, int out_size, void* d_ws, size_t ws_size,
                              hipStream_t stream) {
    (void)n_in; (void)out_size; (void)ws_size;
    const float* x   = (const float*)d_in[0];
    const void*  ei  = d_in[1];
    const float* W1l = (const float*)d_in[2];
    const float* b1  = (const float*)d_in[3];
    const float* W1r = (const float*)d_in[4];
    const float* g1  = (const float*)d_in[5];
    const float* be1 = (const float*)d_in[6];
    const float* W2l = (const float*)d_in[7];
    const float* b2  = (const float*)d_in[8];
    const float* W2r = (const float*)d_in[9];
    const float* g2  = (const float*)d_in[10];
    const float* be2 = (const float*)d_in[11];
    const float* W3l = (const float*)d_in[12];
    const float* b3  = (const float*)d_in[13];
    const float* W3r = (const float*)d_in[14];
    float* out = (float*)d_out;

    const int n_nodes = in_sizes[0] / 64;
    const int n_edges = in_sizes[1] / 2;
    const int nAgg = n_nodes * 64;

    size_t off = 0;
    auto alloc = [&](size_t bytes) {
        void* p = (char*)d_ws + off;
        off = (off + bytes + 255) & ~(size_t)255;
        return p;
    };
    float* agg    = (float*)alloc((size_t)nAgg * 4);
    float* hA     = (float*)alloc((size_t)nAgg * 4);
    float* hB     = (float*)alloc((size_t)nAgg * 4);
    int*   csr    = (int*)  alloc((size_t)n_edges * 4);
    int*   rowptr = (int*)  alloc((size_t)(n_nodes + 1) * 4);
    int*   cursor = (int*)  alloc((size_t)n_nodes * 4);
    int*   deg    = (int*)  alloc((size_t)n_nodes * 4);
    int*   bsum   = (int*)  alloc(1024 * 4);
    int*   boffs  = (int*)  alloc(1024 * 4);
    const int GG = 512;
    double* psum  = (double*)alloc((size_t)GG * 64 * 8);
    double* psq   = (double*)alloc((size_t)GG * 64 * 8);
    float*  mu    = (float*) alloc(64 * 4);
    float*  istd  = (float*) alloc(64 * 4);
    int*    flag  = (int*)   alloc(4);

    const int GP = 256, GH = 1024, GF = 1024, GA = 2048, GN = 1024;
    const int NB = (n_nodes + 255) / 256;  // 196 for 50k nodes (<=1024)
    const int GL3 = (n_nodes + 15) / 16;

    // ---- build CSR once ----
    k_prep <<<GP, 256, 0, stream>>>(deg, n_nodes, (const int*)ei, flag);
    k_hist <<<GH, 256, 0, stream>>>(ei, n_edges, deg, flag);
    k_scan1<<<NB, 256, 0, stream>>>(deg, bsum, n_nodes);
    k_scan2<<<1, 1024, 0, stream>>>(bsum, boffs, NB, rowptr, n_nodes);
    k_scan3<<<NB, 256, 0, stream>>>(deg, boffs, rowptr, cursor, n_nodes);
    k_fill <<<GF, 256, 0, stream>>>(ei, n_edges, cursor, csr, flag);

    // ---- layer 1 ----
    k_aggregate<<<GA, 256, 0, stream>>>(x, rowptr, csr, agg, n_nodes);
    k_gemm64  <<<GG, 256, 0, stream>>>(agg, x, W1l, b1, W1r, hA, psum, psq, n_nodes);
    k_finalize<<<1, 1024, 0, stream>>>(psum, psq, mu, istd, n_nodes, GG);
    k_bnrelu  <<<GN, 256, 0, stream>>>(hA, g1, be1, mu, istd, nAgg / 4);
    // ---- layer 2 ----
    k_aggregate<<<GA, 256, 0, stream>>>(hA, rowptr, csr, agg, n_nodes);
    k_gemm64  <<<GG, 256, 0, stream>>>(agg, hA, W2l, b2, W2r, hB, psum, psq, n_nodes);
    k_finalize<<<1, 1024, 0, stream>>>(psum, psq, mu, istd, n_nodes, GG);
    k_bnrelu  <<<GN, 256, 0, stream>>>(hB, g2, be2, mu, istd, nAgg / 4);
    // ---- layer 3 ----
    k_aggregate<<<GA, 256, 0, stream>>>(hB, rowptr, csr, agg, n_nodes);
    k_l3      <<<GL3, 256, 0, stream>>>(agg, hB, W3l, b3, W3r, out, n_nodes);
}